// Round 1
// baseline (1118.917 us; speedup 1.0000x reference)
//
#include <hip/hip_runtime.h>
#include <stdint.h>

// ---------------------------------------------------------------------------
// DeepSeek-V2 decoder layer, MI355X round 4.
// R3->R4: (a) gemm256 — 256x256/BK=32 ring-4 deep-pipelined GEMM (counted
// vmcnt(4), raw s_barrier, setprio MFMA clusters, XOR-swizzled LDS) for
// gate_up + attention scores; (b) 64x64 float4/ushort8 weight transposes.
// Everything else unchanged. 27 dispatches.
// ---------------------------------------------------------------------------

#define S_   2048
#define D_   2048
#define H_   16
#define QL_  1536
#define KVL_ 512
#define DN_  128
#define DR_  64
#define DV_  128
#define I_   8192
#define SCALE_ 0.07216878364870323f   // (DN+DR)^-0.5

typedef __bf16 bf16x8 __attribute__((ext_vector_type(8)));
typedef float f32x4 __attribute__((ext_vector_type(4)));
typedef unsigned short us8 __attribute__((ext_vector_type(8)));

__device__ __forceinline__ unsigned short f2bf(float f) {
  unsigned int u = __builtin_bit_cast(unsigned int, f);
  u += 0x7fffu + ((u >> 16) & 1u);           // RNE
  return (unsigned short)(u >> 16);
}
__device__ __forceinline__ float bf2f(unsigned short b) {
  unsigned int u = ((unsigned int)b) << 16;
  return __builtin_bit_cast(float, u);
}

__device__ __forceinline__ float block_sum256(float v) {
  __shared__ float red[4];
  #pragma unroll
  for (int o = 32; o; o >>= 1) v += __shfl_xor(v, o);
  __syncthreads();
  if ((threadIdx.x & 63) == 0) red[threadIdx.x >> 6] = v;
  __syncthreads();
  return red[0] + red[1] + red[2] + red[3];
}
__device__ __forceinline__ float block_max256(float v) {
  __shared__ float red[4];
  #pragma unroll
  for (int o = 32; o; o >>= 1) v = fmaxf(v, __shfl_xor(v, o));
  __syncthreads();
  if ((threadIdx.x & 63) == 0) red[threadIdx.x >> 6] = v;
  __syncthreads();
  return fmaxf(fmaxf(red[0], red[1]), fmaxf(red[2], red[3]));
}

__device__ __forceinline__ void gload_lds16(const void* g, void* l) {
  void* gn = const_cast<void*>(g);
  __builtin_amdgcn_global_load_lds(
      (__attribute__((address_space(1))) void*)gn,
      (__attribute__((address_space(3))) void*)l, 16, 0, 0);
}

// ---------------------------------------------------------------------------
// gemm256: C[M,N] = scale * A[M,K](bf16,lda) @ Bt[N,K](bf16,ldb)^T
// 256x256 tile, BK=32, 512 threads = 8 waves (2M x 4N), per-wave 128x64 out.
// Ring-4 LDS (4 x 16KB per matrix = 128 KiB): while computing tile kt
// (slot kt&3), tile kt+1 is fully resident (slot kt+1&3), tile kt+2 is in
// flight (slot kt+2&3 — its previous reader, tile kt-2, finished two
// barriers ago). One counted s_waitcnt vmcnt(4) per tile (the 4 newest
// outstanding loads are tile kt+2's A+B; everything older — i.e. tile
// kt+1 — is forced complete). Raw s_barrier: no compiler vmcnt(0) drain.
// LDS swizzle: row r's 16B chunk c stored at c ^ ((r>>1)&3); applied on the
// GLOBAL source address (global_load_lds dest must stay lane-linear), and
// compensated on the ds_read_b128 side -> 2-way bank aliasing (free).
// Requires: M%256==0, N%256==0, K%32==0, K/32>=2.
// OUT: 1=bf16, 2=silu-pair bf16 (even col=gate, odd=up; writes N/2), 0=f32.
// TRI: blockIdx.x linearizes lower-triangle of the 8x8 (2048/256) grid.
// ---------------------------------------------------------------------------
template <int OUT, int TRI>
__global__ __launch_bounds__(512, 2) void gemm256(
    const unsigned short* __restrict__ A, const unsigned short* __restrict__ Bt,
    void* __restrict__ C, float scale, int M, int N, int K,
    int lda, int ldb, int ldc, long sA, long sB, long sC) {
  __shared__ unsigned short As[4][8192];
  __shared__ unsigned short Bs[4][8192];
  const int b = blockIdx.z;
  int bx = blockIdx.x, by = blockIdx.y;
  if (TRI) {
    const int t = blockIdx.x;
    int i = (int)((sqrtf(8.f * t + 1.f) - 1.f) * 0.5f);
    while ((i + 1) * (i + 2) / 2 <= t) ++i;
    while (i * (i + 1) / 2 > t) --i;
    by = i; bx = t - i * (i + 1) / 2;
  } else {
    // bijective XCD swizzle (m204): XCD k gets a contiguous chunk of the
    // natural (row-major) tile order -> A-panel stays in one XCD's L2.
    int l = by * gridDim.x + bx;
    const int nwg = gridDim.x * gridDim.y;
    const int q = nwg >> 3, r = nwg & 7;
    const int xcd = l & 7, pos = l >> 3;
    l = (xcd < r ? xcd * (q + 1) : r * (q + 1) + (xcd - r) * q) + pos;
    bx = l % gridDim.x; by = l / gridDim.x;
  }
  const int m0 = by * 256, n0 = bx * 256;
  const int tid = threadIdx.x, w = tid >> 6, lane = tid & 63;
  const int wm = w >> 2, wn = w & 3;
  const int fr = lane & 15, fq = lane >> 4;
  const unsigned short* Ab = A + (long)b * sA;
  const unsigned short* Bb = Bt + (long)b * sB;

  // staging: per thread 2 chunks per matrix per tile. chunk id
  // g = (w + 8j)*64 + lane -> LDS bytes g*16 (lane-linear per wave-issue);
  // row = g>>2, chunk pos = g&3, global source chunk = pos ^ ((row>>1)&3).
  long aoff[2], boff[2];
  int loff[2];
  #pragma unroll
  for (int j = 0; j < 2; ++j) {
    const int g = (w + 8 * j) * 64 + lane;
    const int row = g >> 2, c = g & 3;
    const int sc_ = c ^ ((row >> 1) & 3);
    aoff[j] = (long)(m0 + row) * lda + sc_ * 8;
    boff[j] = (long)(n0 + row) * ldb + sc_ * 8;
    loff[j] = g * 8;   // ushort units
  }
  const int NT = K >> 5;

  // prologue: stage tiles 0 and 1; require tile 0 complete, tile 1 in flight.
  #pragma unroll
  for (int t = 0; t < 2; ++t) {
    #pragma unroll
    for (int j = 0; j < 2; ++j)
      gload_lds16(Ab + aoff[j] + t * 32, As[t] + loff[j]);
    #pragma unroll
    for (int j = 0; j < 2; ++j)
      gload_lds16(Bb + boff[j] + t * 32, Bs[t] + loff[j]);
  }
  asm volatile("s_waitcnt vmcnt(4)" ::: "memory");
  asm volatile("s_barrier" ::: "memory");
  __builtin_amdgcn_sched_barrier(0);

  f32x4 acc[8][4] = {};
  const int arow0 = wm * 128 + fr;
  const int brow0 = wn * 64 + fr;

  for (int kt = 0; kt < NT; ++kt) {
    const unsigned short* At = As[kt & 3];
    const unsigned short* Bl = Bs[kt & 3];
    const bool pf = (kt + 2 < NT);
    bf16x8 afrag[4], bfrag[4];
    // ---------------- phase 0: stage A(kt+2) | read B + A-half0 | MFMA ----
    if (pf) {
      #pragma unroll
      for (int j = 0; j < 2; ++j)
        gload_lds16(Ab + aoff[j] + (kt + 2) * 32, As[(kt + 2) & 3] + loff[j]);
    }
    #pragma unroll
    for (int j = 0; j < 4; ++j) {
      const int row = brow0 + j * 16;
      bfrag[j] = *(const bf16x8*)(Bl + row * 32 + (fq ^ ((row >> 1) & 3)) * 8);
    }
    #pragma unroll
    for (int i = 0; i < 4; ++i) {
      const int row = arow0 + i * 16;
      afrag[i] = *(const bf16x8*)(At + row * 32 + (fq ^ ((row >> 1) & 3)) * 8);
    }
    asm volatile("s_barrier" ::: "memory");
    __builtin_amdgcn_sched_barrier(0);
    __builtin_amdgcn_s_setprio(1);
    #pragma unroll
    for (int i = 0; i < 4; ++i)
      #pragma unroll
      for (int j = 0; j < 4; ++j)
        acc[i][j] = __builtin_amdgcn_mfma_f32_16x16x32_bf16(
            afrag[i], bfrag[j], acc[i][j], 0, 0, 0);
    __builtin_amdgcn_s_setprio(0);
    __builtin_amdgcn_sched_barrier(0);
    // ---------------- phase 1: stage B(kt+2) | read A-half1 | vmcnt | MFMA -
    if (pf) {
      #pragma unroll
      for (int j = 0; j < 2; ++j)
        gload_lds16(Bb + boff[j] + (kt + 2) * 32, Bs[(kt + 2) & 3] + loff[j]);
    }
    #pragma unroll
    for (int i = 0; i < 4; ++i) {
      const int row = arow0 + 64 + i * 16;
      afrag[i] = *(const bf16x8*)(At + row * 32 + (fq ^ ((row >> 1) & 3)) * 8);
    }
    if (kt + 1 < NT) {
      // tile-boundary guarantee: tile kt+1 fully landed. In steady state the
      // 4 newest loads are tile kt+2's -> vmcnt(4), never a full drain.
      if (pf) asm volatile("s_waitcnt vmcnt(4)" ::: "memory");
      else    asm volatile("s_waitcnt vmcnt(0)" ::: "memory");
      asm volatile("s_barrier" ::: "memory");
      __builtin_amdgcn_sched_barrier(0);
    }
    __builtin_amdgcn_s_setprio(1);
    #pragma unroll
    for (int i = 0; i < 4; ++i)
      #pragma unroll
      for (int j = 0; j < 4; ++j)
        acc[4 + i][j] = __builtin_amdgcn_mfma_f32_16x16x32_bf16(
            afrag[i], bfrag[j], acc[4 + i][j], 0, 0, 0);
    __builtin_amdgcn_s_setprio(0);
    __builtin_amdgcn_sched_barrier(0);
  }

  const long cb = (long)b * sC;
  #pragma unroll
  for (int ii = 0; ii < 8; ++ii) {
    const int row0 = m0 + wm * 128 + ii * 16 + fq * 4;
    #pragma unroll
    for (int j = 0; j < 4; ++j) {
      const int col = n0 + wn * 64 + j * 16 + fr;
      #pragma unroll
      for (int r = 0; r < 4; ++r) {
        float v = acc[ii][j][r] * scale;
        if (OUT == 2) {
          const float o = __shfl_xor(v, 1);   // partner col (gate<->up)
          const float res = v / (1.f + __expf(-v)) * o;  // valid on even lanes
          if ((fr & 1) == 0)
            ((unsigned short*)C)[cb + (long)(row0 + r) * ldc + (col >> 1)] =
                f2bf(res);
        } else if (OUT == 1) {
          ((unsigned short*)C)[cb + (long)(row0 + r) * ldc + col] = f2bf(v);
        } else {
          ((float*)C)[cb + (long)(row0 + r) * ldc + col] = v;
        }
      }
    }
  }
}

// ---------------------------------------------------------------------------
// GEMM: C[M,N] = scale * A[M,K](bf16,lda) * Bt[N,K](bf16,ldb)^T (+R)
// 128x128 tile, BK=64, 256 threads (4 waves, 64x64 each, 4x4 mfma tiles).
// (unchanged from R3 — used for the shapes whose 256-tile grid would starve)
// ---------------------------------------------------------------------------
template <int OUT, int ADD_RES, int TRI, int CK>
__global__ __launch_bounds__(256) void gemm_bt(
    const unsigned short* __restrict__ A, const unsigned short* __restrict__ Bt,
    void* __restrict__ C, const float* __restrict__ R, float scale,
    int M, int N, int K, int lda, int ldb, int ldc,
    long sA, long sB, long sC) {
  __shared__ unsigned short As[128 * 64];
  __shared__ unsigned short Bs[128 * 64];
  const int b = blockIdx.z;
  int bx = blockIdx.x, by = blockIdx.y;
  if (TRI) {
    const int t = blockIdx.x;
    int i = (int)((sqrtf(8.f * t + 1.f) - 1.f) * 0.5f);
    while ((i + 1) * (i + 2) / 2 <= t) ++i;
    while (i * (i + 1) / 2 > t) --i;
    by = i;
    bx = t - i * (i + 1) / 2;
  }
  const int m0 = by * 128, n0 = bx * 128;
  if (CK) K = min(K, m0 + 128);
  const int tid = threadIdx.x, w = tid >> 6, lane = tid & 63;
  const int wm = (w >> 1) * 64, wn = (w & 1) * 64;
  const int fr = lane & 15;      // m (A) / n (B) within 16-tile
  const int fq = lane >> 4;      // quad
  const int sr = lane >> 3;
  const int sch = (lane & 7) ^ sr;
  const unsigned short* Ab = A + (long)b * sA;
  const unsigned short* Bb = Bt + (long)b * sB;
  long aOff[4], bOff[4];
  #pragma unroll
  for (int i = 0; i < 4; ++i) {
    const int row = w * 32 + i * 8 + sr;
    aOff[i] = (long)(m0 + row) * lda + sch * 8;
    bOff[i] = (long)(n0 + row) * ldb + sch * 8;
  }
  const int ca0 = fq ^ (fr & 7);
  const int ca1 = (4 + fq) ^ (fr & 7);

  f32x4 acc[4][4] = {};

  for (int k0 = 0; k0 < K; k0 += 64) {
    #pragma unroll
    for (int i = 0; i < 4; ++i) {
      gload_lds16(Ab + aOff[i] + k0, As + (w * 32 + i * 8) * 64);
      gload_lds16(Bb + bOff[i] + k0, Bs + (w * 32 + i * 8) * 64);
    }
    __syncthreads();
    #pragma unroll
    for (int s = 0; s < 2; ++s) {
      const int cc = s ? ca1 : ca0;
      bf16x8 af[4], bf[4];
      #pragma unroll
      for (int i = 0; i < 4; ++i)
        af[i] = *(const bf16x8*)(As + (wm + i * 16 + fr) * 64 + cc * 8);
      #pragma unroll
      for (int j = 0; j < 4; ++j)
        bf[j] = *(const bf16x8*)(Bs + (wn + j * 16 + fr) * 64 + cc * 8);
      #pragma unroll
      for (int i = 0; i < 4; ++i)
        #pragma unroll
        for (int j = 0; j < 4; ++j)
          acc[i][j] = __builtin_amdgcn_mfma_f32_16x16x32_bf16(af[i], bf[j],
                                                              acc[i][j], 0, 0, 0);
    }
    __syncthreads();
  }

  const long cb = (long)b * sC;
  #pragma unroll
  for (int i = 0; i < 4; ++i) {
    const int row0 = m0 + wm + i * 16 + fq * 4;
    #pragma unroll
    for (int j = 0; j < 4; ++j) {
      const int col = n0 + wn + j * 16 + fr;
      #pragma unroll
      for (int r = 0; r < 4; ++r) {
        float v = acc[i][j][r] * scale;
        if (OUT == 2) {
          const float o = __shfl_xor(v, 1);
          const float res = v / (1.f + __expf(-v)) * o;
          if (((fr & 1) == 0) && col < N)
            ((unsigned short*)C)[cb + (long)(row0 + r) * ldc + (col >> 1)] =
                f2bf(res);
        } else {
          if (col < N) {
            const long idx = cb + (long)(row0 + r) * ldc + col;
            float vv = v;
            if (ADD_RES) vv += R[idx];
            if (OUT == 1) ((unsigned short*)C)[idx] = f2bf(vv);
            else          ((float*)C)[idx] = vv;
          }
        }
      }
    }
  }
}

// ---------------------------------------------------------------------------
// transpose + convert, 64x64 tile: in fp32 [R,C] -> out bf16 [C,R].
// float4 loads (16B/lane), ushort8 stores (16B/lane), 2-way LDS aliasing only.
// ILV=1: gate_up interleave — out row n = ((c & (I-1))<<1) | (c>>13).
// R, C multiples of 64.
// ---------------------------------------------------------------------------
template <int ILV>
__global__ __launch_bounds__(256) void transpose64(
    const float* __restrict__ in, unsigned short* __restrict__ out,
    int Rr, int Cc, long sIn, long sOut) {
  __shared__ float t[64][65];
  const int b = blockIdx.z;
  in  += (long)b * sIn;
  out += (long)b * sOut;
  const int c0 = blockIdx.x * 64, r0 = blockIdx.y * 64;
  const int tid = threadIdx.x;
  const int rl = tid >> 4;        // 0..15
  const int cq = tid & 15;        // 0..15
  #pragma unroll
  for (int rr = 0; rr < 4; ++rr) {
    const int r = rl + rr * 16;
    const float4 v = *(const float4*)(in + (long)(r0 + r) * Cc + c0 + cq * 4);
    t[cq * 4 + 0][r] = v.x;
    t[cq * 4 + 1][r] = v.y;
    t[cq * 4 + 2][r] = v.z;
    t[cq * 4 + 3][r] = v.w;
  }
  __syncthreads();
  const int c = tid >> 2;         // 0..63
  const int rb = (tid & 3) * 16;  // 0,16,32,48
  const int cg = c0 + c;
  const long nrow = ILV ? (long)(((cg & (I_ - 1)) << 1) | (cg >> 13)) : (long)cg;
  #pragma unroll
  for (int i = 0; i < 2; ++i) {
    us8 o;
    #pragma unroll
    for (int jj = 0; jj < 8; ++jj) o[jj] = f2bf(t[c][rb + i * 8 + jj]);
    *(us8*)(out + nrow * Rr + r0 + rb + i * 8) = o;
  }
}

// rmsnorm rows: y_bf16 = x * rsqrt(mean(x^2)+eps) * w
__global__ void rmsnorm_k(const float* __restrict__ x, const float* __restrict__ w,
                          unsigned short* __restrict__ y, int C) {
  const int row = blockIdx.x, tid = threadIdx.x;
  const float* xr = x + (long)row * C;
  float ss = 0.f;
  for (int c = tid; c < C; c += 256) { float v = xr[c]; ss += v * v; }
  ss = block_sum256(ss);
  const float rms = rsqrtf(ss / C + 1e-6f);
  for (int c = tid; c < C; c += 256)
    y[(long)row * C + c] = f2bf(xr[c] * rms * w[c]);
}

// q postprocess: split q (S,3072) into qnope bf16 (S,H*128) and roped pe into
// qf[h][s][512..575]
__global__ void q_post(const float* __restrict__ q, const float* __restrict__ cs,
                       const float* __restrict__ sn, unsigned short* __restrict__ qnope,
                       unsigned short* __restrict__ qf) {
  const int s = blockIdx.x, tid = threadIdx.x;
  const float* qr = q + (long)s * 3072;
  for (int c = tid; c < 3072; c += 256) {
    const int h = c / 192, d = c % 192;
    if (d < 128) {
      qnope[(long)s * 2048 + h * 128 + d] = f2bf(qr[c]);
    } else {
      const int j = d - 128;
      const float x = qr[c];
      const float rot = (j < 32) ? -qr[h * 192 + 128 + j + 32]
                                 :  qr[h * 192 + 128 + j - 32];
      const float v = x * cs[s * 64 + j] + rot * sn[s * 64 + j];
      qf[(long)h * (S_ * 576) + (long)s * 576 + 512 + j] = f2bf(v);
    }
  }
}

// kv postprocess: rmsnorm first 512 -> kf[:, :512] and klat^T; rope last 64.
__global__ void kv_post(const float* __restrict__ kv, const float* __restrict__ w,
                        const float* __restrict__ cs, const float* __restrict__ sn,
                        unsigned short* __restrict__ kf, unsigned short* __restrict__ klt) {
  const int s = blockIdx.x, tid = threadIdx.x;
  const float* kr = kv + (long)s * 576;
  float ss = 0.f;
  for (int c = tid; c < 512; c += 256) { float v = kr[c]; ss += v * v; }
  ss = block_sum256(ss);
  const float rms = rsqrtf(ss / 512.f + 1e-6f);
  for (int c = tid; c < 576; c += 256) {
    if (c < 512) {
      const float v = kr[c] * rms * w[c];
      const unsigned short bv = f2bf(v);
      kf[(long)s * 576 + c] = bv;
      klt[(long)c * S_ + s] = bv;
    } else {
      const int j = c - 512;
      const float x = kr[c];
      const float rot = (j < 32) ? -kr[512 + j + 32] : kr[512 + j - 32];
      kf[(long)s * 576 + c] = f2bf(x * cs[s * 64 + j] + rot * sn[s * 64 + j]);
    }
  }
}

// causal softmax IN-PLACE on bf16 scores. Row r: softmax over c<=r; zeros for
// c in (r, kmax), kmax = 128*ceil((r+1)/128) (cols the causal PV GEMM reads).
__global__ void softmax_causal_ip(unsigned short* __restrict__ sc, long hstride) {
  const int row = blockIdx.x, tid = threadIdx.x;
  unsigned short* sr = sc + (long)blockIdx.z * hstride + (long)row * S_;
  const int n = row + 1;
  const int kmax = ((row >> 7) + 1) << 7;
  float mx = -1e30f;
  for (int c = tid; c < n; c += 256) mx = fmaxf(mx, bf2f(sr[c]));
  mx = block_max256(mx);
  float e[8];
  float sum = 0.f;
  #pragma unroll
  for (int k = 0; k < 8; ++k) {
    const int c = tid + k * 256;
    if (c < n) { e[k] = __expf(bf2f(sr[c]) - mx); sum += e[k]; }
  }
  sum = block_sum256(sum);   // internal syncthreads: all reads of sr done
  const float inv = 1.f / sum;
  #pragma unroll
  for (int k = 0; k < 8; ++k) {
    const int c = tid + k * 256;
    if (c < n) sr[c] = f2bf(e[k] * inv);
    else if (c < kmax) sr[c] = 0;
  }
}

// ---------------------------------------------------------------------------
extern "C" void kernel_launch(void* const* d_in, const int* in_sizes, int n_in,
                              void* d_out, int out_size, void* d_ws, size_t ws_size,
                              hipStream_t stream) {
  const float* hs   = (const float*)d_in[0];
  const float* cs   = (const float*)d_in[1];
  const float* sn   = (const float*)d_in[2];
  const float* ln1  = (const float*)d_in[3];
  const float* qaw  = (const float*)d_in[4];
  const float* qaln = (const float*)d_in[5];
  const float* qbw  = (const float*)d_in[6];
  const float* kvaw = (const float*)d_in[7];
  const float* kvln = (const float*)d_in[8];
  const float* kcw  = (const float*)d_in[9];
  const float* vcw  = (const float*)d_in[10];
  const float* ow   = (const float*)d_in[11];
  const float* ln2  = (const float*)d_in[12];
  const float* guw  = (const float*)d_in[13];
  const float* dww  = (const float*)d_in[14];
  float* out = (float*)d_out;
  char* ws = (char*)d_ws;

  // ---- workspace layout (bytes); high-water 183697408 ----------------------
  // pre-attention (dead before scores are written)
  unsigned short* hbf   = (unsigned short*)(ws + 0);           // S*D bf16 8MB
  float*          qa    = (float*)(ws + 8388608);              // S*QL f32
  unsigned short* qan   = (unsigned short*)(ws + 20971520);    // S*QL bf16
  float*          q     = (float*)(ws + 27262976);             // S*3072 f32
  unsigned short* qnope = (unsigned short*)(ws + 52428800);    // S*2048 bf16 ends 60817408
  // attention
  unsigned short* sc    = (unsigned short*)(ws + 0);           // 8 heads S*S bf16 = 64MB
  unsigned short* qf    = (unsigned short*)(ws + 67108864);    // H*S*576 bf16 ends 104857600
  float*          kv    = (float*)(ws + 104857600);            // S*576 f32
  unsigned short* kf    = (unsigned short*)(ws + 109576192);   // S*576 bf16
  unsigned short* klt   = (unsigned short*)(ws + 111935488);   // 512*S bf16
  unsigned short* wt2   = (unsigned short*)(ws + 114032640);   // vc^T 2MB
  unsigned short* wt    = (unsigned short*)(ws + 116129792);   // weight scratch (<=67MB, ends 183697408)
  unsigned short* olat  = (unsigned short*)(ws + 116129792);   // H*S*512 bf16 (aliases wt; kc^T dead first,
                                                               // wt reused only after olat consumed)
  // post-attention
  unsigned short* obf   = (unsigned short*)(ws + 0);           // S*2048 bf16 8MB
  float*          hidden= (float*)(ws + 8388608);              // S*D f32 ends 25165824
  unsigned short* x2    = (unsigned short*)(ws + 25165824);    // S*D bf16 ends 33554432
  unsigned short* mlp   = (unsigned short*)(ws + 33554432);    // S*I bf16 ends 67108864

  const dim3 B256(256), B512(512);

  // 1. h = rmsnorm(hidden_states, ln1)
  rmsnorm_k<<<S_, B256, 0, stream>>>(hs, ln1, hbf, D_);
  // 2-3. q_a = h @ q_a_w
  transpose64<0><<<dim3(QL_/64, D_/64, 1), B256, 0, stream>>>(qaw, wt, D_, QL_, 0, 0);
  gemm_bt<0,0,0,0><<<dim3(QL_/128, S_/128, 1), B256, 0, stream>>>(
      hbf, wt, qa, nullptr, 1.f, S_, QL_, D_, D_, D_, QL_, 0, 0, 0);
  // 4. q_a_norm
  rmsnorm_k<<<S_, B256, 0, stream>>>(qa, qaln, qan, QL_);
  // 5-6. q = qan @ q_b_w
  transpose64<0><<<dim3(3072/64, QL_/64, 1), B256, 0, stream>>>(qbw, wt, QL_, 3072, 0, 0);
  gemm_bt<0,0,0,0><<<dim3(3072/128, S_/128, 1), B256, 0, stream>>>(
      qan, wt, q, nullptr, 1.f, S_, 3072, QL_, QL_, QL_, 3072, 0, 0, 0);
  // 7. split q -> qnope bf16, rope(q_pe) -> qf[...,512:]
  q_post<<<S_, B256, 0, stream>>>(q, cs, sn, qnope, qf);
  // 8-9. kv = h @ kv_a_w
  transpose64<0><<<dim3(576/64, D_/64, 1), B256, 0, stream>>>(kvaw, wt, D_, 576, 0, 0);
  gemm_bt<0,0,0,0><<<dim3(5, S_/128, 1), B256, 0, stream>>>(
      hbf, wt, kv, nullptr, 1.f, S_, 576, D_, D_, D_, 576, 0, 0, 0);
  // 10. kv_post: k_lat rmsnorm + transpose, k_pe rope
  kv_post<<<S_, B256, 0, stream>>>(kv, kvln, cs, sn, kf, klt);
  // 11-12. transpose kc_w (128x512 -> 512x128 per head) and vc_w (512x128 -> 128x512)
  transpose64<0><<<dim3(512/64, 128/64, H_), B256, 0, stream>>>(kcw, wt, 128, 512, 65536, 65536);
  transpose64<0><<<dim3(128/64, 512/64, H_), B256, 0, stream>>>(vcw, wt2, 512, 128, 65536, 65536);
  // 13. q_lat[h] = qnope[:,h,:] @ kc_w[h] -> qf[h][:, :512]
  gemm_bt<1,0,0,0><<<dim3(4, S_/128, H_), B256, 0, stream>>>(
      qnope, wt, qf, nullptr, 1.f, S_, 512, 128, 2048, 128, 576,
      128, 65536, (long)S_ * 576);
  // 14-19. attention, 2 groups of 8 heads. scores via 256^2 deep-pipe GEMM
  // (lower-triangle of the 8x8 tile grid; cols above the 128-aligned kmax
  // hold garbage that softmax/PV provably never read).
  for (int g = 0; g < 2; ++g) {
    const unsigned short* qfg = qf + (long)g * 8 * S_ * 576;
    gemm256<1,1><<<dim3(36, 1, 8), B512, 0, stream>>>(
        qfg, kf, sc, SCALE_, S_, S_, 576, 576, 576, S_,
        (long)S_ * 576, 0, (long)S_ * S_);
    softmax_causal_ip<<<dim3(S_, 1, 8), B256, 0, stream>>>(sc, (long)S_ * S_);
    gemm_bt<1,0,0,1><<<dim3(4, 16, 8), B256, 0, stream>>>(
        sc, klt, olat + (long)g * 8 * S_ * 512, nullptr, 1.f,
        S_, 512, S_, S_, S_, 512, (long)S_ * S_, 0, (long)S_ * 512);
  }
  // 20. o[:, h*128:...] = o_lat[h] @ vc_w[h]
  gemm_bt<1,0,0,0><<<dim3(1, S_/128, H_), B256, 0, stream>>>(
      olat, wt2, obf, nullptr, 1.f, S_, 128, 512, 512, 512, 2048,
      (long)S_ * 512, 65536, 128);
  // 21-22. hidden = hs + o @ o_w   (residual fused into GEMM epilogue)
  transpose64<0><<<dim3(D_/64, D_/64, 1), B256, 0, stream>>>(ow, wt, D_, D_, 0, 0);
  gemm_bt<0,1,0,0><<<dim3(D_/128, S_/128, 1), B256, 0, stream>>>(
      obf, wt, hidden, hs, 1.f, S_, D_, D_, D_, D_, D_, 0, 0, 0);
  // 23. x2 = rmsnorm(hidden, ln2)
  rmsnorm_k<<<S_, B256, 0, stream>>>(hidden, ln2, x2, D_);
  // 24-25. mlp = silu(x2@gate) * (x2@up) via 256^2 deep-pipe GEMM,
  // silu fused in epilogue, interleaved weight cols, XCD-swizzled grid.
  transpose64<1><<<dim3(2 * I_ / 64, D_/64, 1), B256, 0, stream>>>(guw, wt, D_, 2 * I_, 0, 0);
  gemm256<2,0><<<dim3(2 * I_ / 256, S_/256, 1), B512, 0, stream>>>(
      x2, wt, mlp, 1.f, S_, 2 * I_, D_, D_, D_, I_, 0, 0, 0);
  // 26-27. out = hidden + mlp @ down_w
  transpose64<0><<<dim3(D_/64, I_/64, 1), B256, 0, stream>>>(dww, wt, I_, D_, 0, 0);
  gemm_bt<0,1,0,0><<<dim3(D_/128, S_/128, 1), B256, 0, stream>>>(
      mlp, wt, out, hidden, 1.f, S_, D_, I_, I_, I_, D_, 0, 0, 0);
}

// Round 2
// 1106.817 us; speedup vs baseline: 1.0109x; 1.0109x over previous
//
#include <hip/hip_runtime.h>
#include <stdint.h>

// ---------------------------------------------------------------------------
// DeepSeek-V2 decoder layer, MI355X round 5.
// R4->R5: gemm256 pipeline deepened (ring-4 used at depth 3: prologue stages
// tiles 0-2, tile kt stages kt+3, tile-boundary wait vmcnt(8) — ~850cy of
// latency cover vs 320 before), explicit lgkmcnt(0) fence before the
// boundary barrier (slot kt&3 is overwritten by kt+1's phase-0 stage), and
// column-major XCD chunking (each XCD owns 8 N-columns: B-panel L2-resident,
// A L3-resident; kills the 3.7x overfetch of row-major chunking).
// Everything else identical to R4. 27 dispatches.
// ---------------------------------------------------------------------------

#define S_   2048
#define D_   2048
#define H_   16
#define QL_  1536
#define KVL_ 512
#define DN_  128
#define DR_  64
#define DV_  128
#define I_   8192
#define SCALE_ 0.07216878364870323f   // (DN+DR)^-0.5

typedef __bf16 bf16x8 __attribute__((ext_vector_type(8)));
typedef float f32x4 __attribute__((ext_vector_type(4)));
typedef unsigned short us8 __attribute__((ext_vector_type(8)));

__device__ __forceinline__ unsigned short f2bf(float f) {
  unsigned int u = __builtin_bit_cast(unsigned int, f);
  u += 0x7fffu + ((u >> 16) & 1u);           // RNE
  return (unsigned short)(u >> 16);
}
__device__ __forceinline__ float bf2f(unsigned short b) {
  unsigned int u = ((unsigned int)b) << 16;
  return __builtin_bit_cast(float, u);
}

__device__ __forceinline__ float block_sum256(float v) {
  __shared__ float red[4];
  #pragma unroll
  for (int o = 32; o; o >>= 1) v += __shfl_xor(v, o);
  __syncthreads();
  if ((threadIdx.x & 63) == 0) red[threadIdx.x >> 6] = v;
  __syncthreads();
  return red[0] + red[1] + red[2] + red[3];
}
__device__ __forceinline__ float block_max256(float v) {
  __shared__ float red[4];
  #pragma unroll
  for (int o = 32; o; o >>= 1) v = fmaxf(v, __shfl_xor(v, o));
  __syncthreads();
  if ((threadIdx.x & 63) == 0) red[threadIdx.x >> 6] = v;
  __syncthreads();
  return fmaxf(fmaxf(red[0], red[1]), fmaxf(red[2], red[3]));
}

__device__ __forceinline__ void gload_lds16(const void* g, void* l) {
  void* gn = const_cast<void*>(g);
  __builtin_amdgcn_global_load_lds(
      (__attribute__((address_space(1))) void*)gn,
      (__attribute__((address_space(3))) void*)l, 16, 0, 0);
}

// ---------------------------------------------------------------------------
// gemm256: C[M,N] = scale * A[M,K](bf16,lda) @ Bt[N,K](bf16,ldb)^T
// 256x256 tile, BK=32, 512 threads = 8 waves (2M x 4N), per-wave 128x64 out.
// Ring-4 LDS at pipeline depth 3: while computing tile kt (slot kt&3),
// tile kt+1 is resident, tiles kt+2 and kt+3 are in flight (their slots'
// previous readers finished >=1 barrier ago). Tile-boundary wait is
// s_waitcnt vmcnt(8): the 8 newest outstanding loads (per wave: 2 A + 2 B
// per tile) are kt+2's and kt+3's; everything older — tile kt+1 — is forced
// complete. Explicit lgkmcnt(0) before the boundary barrier: slot kt&3 is
// overwritten by tile kt+1's phase-0 stage (of tile kt+4), so all fragment
// reads must be register-resident before any wave crosses.
// LDS swizzle: row r's 16B chunk c stored at c ^ ((r>>1)&3); applied on the
// GLOBAL source address (global_load_lds dest must stay lane-linear),
// compensated on the ds_read_b128 side -> 2-way bank aliasing (free).
// Requires: M%256==0, N%256==0, K%32==0, K/32>=3.
// OUT: 1=bf16, 2=silu-pair bf16 (even col=gate, odd=up; writes N/2), 0=f32.
// TRI: blockIdx.x linearizes lower-triangle of the 8x8 (2048/256) grid.
// non-TRI: column-major XCD chunking (M fastest within an XCD's chunk).
// ---------------------------------------------------------------------------
template <int OUT, int TRI>
__global__ __launch_bounds__(512, 2) void gemm256(
    const unsigned short* __restrict__ A, const unsigned short* __restrict__ Bt,
    void* __restrict__ C, float scale, int M, int N, int K,
    int lda, int ldb, int ldc, long sA, long sB, long sC) {
  __shared__ unsigned short As[4][8192];
  __shared__ unsigned short Bs[4][8192];
  const int b = blockIdx.z;
  int bx = blockIdx.x, by = blockIdx.y;
  if (TRI) {
    const int t = blockIdx.x;
    int i = (int)((sqrtf(8.f * t + 1.f) - 1.f) * 0.5f);
    while ((i + 1) * (i + 2) / 2 <= t) ++i;
    while (i * (i + 1) / 2 > t) --i;
    by = i; bx = t - i * (i + 1) / 2;
  } else {
    // bijective XCD chunking over the COLUMN-major tile order: XCD k gets a
    // contiguous run of (N-col, all M-rows) tiles -> its 1MB B-panels stay in
    // its private L2 (8 M-tiles reuse each), A (8MB) stays in L3.
    const int L = blockIdx.y * gridDim.x + blockIdx.x;  // HW dispatch order
    const int nwg = gridDim.x * gridDim.y;
    const int q = nwg >> 3, r = nwg & 7;
    const int xcd = L & 7, pos = L >> 3;
    const int n = (xcd < r ? xcd * (q + 1) : r * (q + 1) + (xcd - r) * q) + pos;
    bx = n / gridDim.y;       // N-tile (slow)
    by = n - bx * gridDim.y;  // M-tile (fast)
  }
  const int m0 = by * 256, n0 = bx * 256;
  const int tid = threadIdx.x, w = tid >> 6, lane = tid & 63;
  const int wm = w >> 2, wn = w & 3;
  const int fr = lane & 15, fq = lane >> 4;
  const unsigned short* Ab = A + (long)b * sA;
  const unsigned short* Bb = Bt + (long)b * sB;

  // staging: per thread 2 chunks per matrix per tile. chunk id
  // g = (w + 8j)*64 + lane -> LDS bytes g*16 (lane-linear per wave-issue);
  // row = g>>2, chunk pos = g&3, global source chunk = pos ^ ((row>>1)&3).
  long aoff[2], boff[2];
  int loff[2];
  #pragma unroll
  for (int j = 0; j < 2; ++j) {
    const int g = (w + 8 * j) * 64 + lane;
    const int row = g >> 2, c = g & 3;
    const int sc_ = c ^ ((row >> 1) & 3);
    aoff[j] = (long)(m0 + row) * lda + sc_ * 8;
    boff[j] = (long)(n0 + row) * ldb + sc_ * 8;
    loff[j] = g * 8;   // ushort units
  }
  const int NT = K >> 5;

  // prologue: stage tiles 0,1,2 (12 loads/wave); vmcnt(8) -> tile 0 complete,
  // tiles 1,2 in flight.
  #pragma unroll
  for (int t = 0; t < 3; ++t) {
    #pragma unroll
    for (int j = 0; j < 2; ++j)
      gload_lds16(Ab + aoff[j] + t * 32, As[t] + loff[j]);
    #pragma unroll
    for (int j = 0; j < 2; ++j)
      gload_lds16(Bb + boff[j] + t * 32, Bs[t] + loff[j]);
  }
  asm volatile("s_waitcnt vmcnt(8)" ::: "memory");
  asm volatile("s_barrier" ::: "memory");
  __builtin_amdgcn_sched_barrier(0);

  f32x4 acc[8][4] = {};
  const int arow0 = wm * 128 + fr;
  const int brow0 = wn * 64 + fr;

  for (int kt = 0; kt < NT; ++kt) {
    const unsigned short* At = As[kt & 3];
    const unsigned short* Bl = Bs[kt & 3];
    const bool pf = (kt + 3 < NT);
    bf16x8 afrag[4], bfrag[4];
    // ---- phase 0: stage A(kt+3) | read B + A-half0 | MFMA -----------------
    if (pf) {
      #pragma unroll
      for (int j = 0; j < 2; ++j)
        gload_lds16(Ab + aoff[j] + (kt + 3) * 32, As[(kt + 3) & 3] + loff[j]);
    }
    #pragma unroll
    for (int j = 0; j < 4; ++j) {
      const int row = brow0 + j * 16;
      bfrag[j] = *(const bf16x8*)(Bl + row * 32 + (fq ^ ((row >> 1) & 3)) * 8);
    }
    #pragma unroll
    for (int i = 0; i < 4; ++i) {
      const int row = arow0 + i * 16;
      afrag[i] = *(const bf16x8*)(At + row * 32 + (fq ^ ((row >> 1) & 3)) * 8);
    }
    asm volatile("s_barrier" ::: "memory");
    __builtin_amdgcn_sched_barrier(0);
    __builtin_amdgcn_s_setprio(1);
    #pragma unroll
    for (int i = 0; i < 4; ++i)
      #pragma unroll
      for (int j = 0; j < 4; ++j)
        acc[i][j] = __builtin_amdgcn_mfma_f32_16x16x32_bf16(
            afrag[i], bfrag[j], acc[i][j], 0, 0, 0);
    __builtin_amdgcn_s_setprio(0);
    __builtin_amdgcn_sched_barrier(0);
    // ---- phase 1: stage B(kt+3) | read A-half1 | fence | boundary | MFMA --
    if (pf) {
      #pragma unroll
      for (int j = 0; j < 2; ++j)
        gload_lds16(Bb + boff[j] + (kt + 3) * 32, Bs[(kt + 3) & 3] + loff[j]);
    }
    #pragma unroll
    for (int i = 0; i < 4; ++i) {
      const int row = arow0 + 64 + i * 16;
      afrag[i] = *(const bf16x8*)(At + row * 32 + (fq ^ ((row >> 1) & 3)) * 8);
    }
    // all reads of slot kt&3 must be in registers before any wave crosses the
    // boundary barrier (tile kt+1's phase-0 stage overwrites this slot).
    asm volatile("s_waitcnt lgkmcnt(0)" ::: "memory");
    __builtin_amdgcn_sched_barrier(0);
    if (kt + 1 < NT) {
      // boundary: tile kt+1 fully landed. Steady state: the 8 newest loads
      // are tiles kt+2,kt+3 -> vmcnt(8); tail drains 4 -> 0.
      if (kt + 3 < NT)      asm volatile("s_waitcnt vmcnt(8)" ::: "memory");
      else if (kt + 2 < NT) asm volatile("s_waitcnt vmcnt(4)" ::: "memory");
      else                  asm volatile("s_waitcnt vmcnt(0)" ::: "memory");
      asm volatile("s_barrier" ::: "memory");
      __builtin_amdgcn_sched_barrier(0);
    }
    __builtin_amdgcn_s_setprio(1);
    #pragma unroll
    for (int i = 0; i < 4; ++i)
      #pragma unroll
      for (int j = 0; j < 4; ++j)
        acc[4 + i][j] = __builtin_amdgcn_mfma_f32_16x16x32_bf16(
            afrag[i], bfrag[j], acc[4 + i][j], 0, 0, 0);
    __builtin_amdgcn_s_setprio(0);
    __builtin_amdgcn_sched_barrier(0);
  }

  const long cb = (long)b * sC;
  #pragma unroll
  for (int ii = 0; ii < 8; ++ii) {
    const int row0 = m0 + wm * 128 + ii * 16 + fq * 4;
    #pragma unroll
    for (int j = 0; j < 4; ++j) {
      const int col = n0 + wn * 64 + j * 16 + fr;
      #pragma unroll
      for (int r = 0; r < 4; ++r) {
        float v = acc[ii][j][r] * scale;
        if (OUT == 2) {
          const float o = __shfl_xor(v, 1);   // partner col (gate<->up)
          const float res = v / (1.f + __expf(-v)) * o;  // valid on even lanes
          if ((fr & 1) == 0)
            ((unsigned short*)C)[cb + (long)(row0 + r) * ldc + (col >> 1)] =
                f2bf(res);
        } else if (OUT == 1) {
          ((unsigned short*)C)[cb + (long)(row0 + r) * ldc + col] = f2bf(v);
        } else {
          ((float*)C)[cb + (long)(row0 + r) * ldc + col] = v;
        }
      }
    }
  }
}

// ---------------------------------------------------------------------------
// GEMM: C[M,N] = scale * A[M,K](bf16,lda) * Bt[N,K](bf16,ldb)^T (+R)
// 128x128 tile, BK=64, 256 threads (4 waves, 64x64 each, 4x4 mfma tiles).
// (unchanged — used for the shapes whose 256-tile grid would starve)
// ---------------------------------------------------------------------------
template <int OUT, int ADD_RES, int TRI, int CK>
__global__ __launch_bounds__(256) void gemm_bt(
    const unsigned short* __restrict__ A, const unsigned short* __restrict__ Bt,
    void* __restrict__ C, const float* __restrict__ R, float scale,
    int M, int N, int K, int lda, int ldb, int ldc,
    long sA, long sB, long sC) {
  __shared__ unsigned short As[128 * 64];
  __shared__ unsigned short Bs[128 * 64];
  const int b = blockIdx.z;
  int bx = blockIdx.x, by = blockIdx.y;
  if (TRI) {
    const int t = blockIdx.x;
    int i = (int)((sqrtf(8.f * t + 1.f) - 1.f) * 0.5f);
    while ((i + 1) * (i + 2) / 2 <= t) ++i;
    while (i * (i + 1) / 2 > t) --i;
    by = i;
    bx = t - i * (i + 1) / 2;
  }
  const int m0 = by * 128, n0 = bx * 128;
  if (CK) K = min(K, m0 + 128);
  const int tid = threadIdx.x, w = tid >> 6, lane = tid & 63;
  const int wm = (w >> 1) * 64, wn = (w & 1) * 64;
  const int fr = lane & 15;      // m (A) / n (B) within 16-tile
  const int fq = lane >> 4;      // quad
  const int sr = lane >> 3;
  const int sch = (lane & 7) ^ sr;
  const unsigned short* Ab = A + (long)b * sA;
  const unsigned short* Bb = Bt + (long)b * sB;
  long aOff[4], bOff[4];
  #pragma unroll
  for (int i = 0; i < 4; ++i) {
    const int row = w * 32 + i * 8 + sr;
    aOff[i] = (long)(m0 + row) * lda + sch * 8;
    bOff[i] = (long)(n0 + row) * ldb + sch * 8;
  }
  const int ca0 = fq ^ (fr & 7);
  const int ca1 = (4 + fq) ^ (fr & 7);

  f32x4 acc[4][4] = {};

  for (int k0 = 0; k0 < K; k0 += 64) {
    #pragma unroll
    for (int i = 0; i < 4; ++i) {
      gload_lds16(Ab + aOff[i] + k0, As + (w * 32 + i * 8) * 64);
      gload_lds16(Bb + bOff[i] + k0, Bs + (w * 32 + i * 8) * 64);
    }
    __syncthreads();
    #pragma unroll
    for (int s = 0; s < 2; ++s) {
      const int cc = s ? ca1 : ca0;
      bf16x8 af[4], bf[4];
      #pragma unroll
      for (int i = 0; i < 4; ++i)
        af[i] = *(const bf16x8*)(As + (wm + i * 16 + fr) * 64 + cc * 8);
      #pragma unroll
      for (int j = 0; j < 4; ++j)
        bf[j] = *(const bf16x8*)(Bs + (wn + j * 16 + fr) * 64 + cc * 8);
      #pragma unroll
      for (int i = 0; i < 4; ++i)
        #pragma unroll
        for (int j = 0; j < 4; ++j)
          acc[i][j] = __builtin_amdgcn_mfma_f32_16x16x32_bf16(af[i], bf[j],
                                                              acc[i][j], 0, 0, 0);
    }
    __syncthreads();
  }

  const long cb = (long)b * sC;
  #pragma unroll
  for (int i = 0; i < 4; ++i) {
    const int row0 = m0 + wm + i * 16 + fq * 4;
    #pragma unroll
    for (int j = 0; j < 4; ++j) {
      const int col = n0 + wn + j * 16 + fr;
      #pragma unroll
      for (int r = 0; r < 4; ++r) {
        float v = acc[i][j][r] * scale;
        if (OUT == 2) {
          const float o = __shfl_xor(v, 1);
          const float res = v / (1.f + __expf(-v)) * o;
          if (((fr & 1) == 0) && col < N)
            ((unsigned short*)C)[cb + (long)(row0 + r) * ldc + (col >> 1)] =
                f2bf(res);
        } else {
          if (col < N) {
            const long idx = cb + (long)(row0 + r) * ldc + col;
            float vv = v;
            if (ADD_RES) vv += R[idx];
            if (OUT == 1) ((unsigned short*)C)[idx] = f2bf(vv);
            else          ((float*)C)[idx] = vv;
          }
        }
      }
    }
  }
}

// ---------------------------------------------------------------------------
// transpose + convert, 64x64 tile: in fp32 [R,C] -> out bf16 [C,R].
// float4 loads (16B/lane), ushort8 stores (16B/lane), 2-way LDS aliasing only.
// ILV=1: gate_up interleave — out row n = ((c & (I-1))<<1) | (c>>13).
// R, C multiples of 64.
// ---------------------------------------------------------------------------
template <int ILV>
__global__ __launch_bounds__(256) void transpose64(
    const float* __restrict__ in, unsigned short* __restrict__ out,
    int Rr, int Cc, long sIn, long sOut) {
  __shared__ float t[64][65];
  const int b = blockIdx.z;
  in  += (long)b * sIn;
  out += (long)b * sOut;
  const int c0 = blockIdx.x * 64, r0 = blockIdx.y * 64;
  const int tid = threadIdx.x;
  const int rl = tid >> 4;        // 0..15
  const int cq = tid & 15;        // 0..15
  #pragma unroll
  for (int rr = 0; rr < 4; ++rr) {
    const int r = rl + rr * 16;
    const float4 v = *(const float4*)(in + (long)(r0 + r) * Cc + c0 + cq * 4);
    t[cq * 4 + 0][r] = v.x;
    t[cq * 4 + 1][r] = v.y;
    t[cq * 4 + 2][r] = v.z;
    t[cq * 4 + 3][r] = v.w;
  }
  __syncthreads();
  const int c = tid >> 2;         // 0..63
  const int rb = (tid & 3) * 16;  // 0,16,32,48
  const int cg = c0 + c;
  const long nrow = ILV ? (long)(((cg & (I_ - 1)) << 1) | (cg >> 13)) : (long)cg;
  #pragma unroll
  for (int i = 0; i < 2; ++i) {
    us8 o;
    #pragma unroll
    for (int jj = 0; jj < 8; ++jj) o[jj] = f2bf(t[c][rb + i * 8 + jj]);
    *(us8*)(out + nrow * Rr + r0 + rb + i * 8) = o;
  }
}

// rmsnorm rows: y_bf16 = x * rsqrt(mean(x^2)+eps) * w
__global__ void rmsnorm_k(const float* __restrict__ x, const float* __restrict__ w,
                          unsigned short* __restrict__ y, int C) {
  const int row = blockIdx.x, tid = threadIdx.x;
  const float* xr = x + (long)row * C;
  float ss = 0.f;
  for (int c = tid; c < C; c += 256) { float v = xr[c]; ss += v * v; }
  ss = block_sum256(ss);
  const float rms = rsqrtf(ss / C + 1e-6f);
  for (int c = tid; c < C; c += 256)
    y[(long)row * C + c] = f2bf(xr[c] * rms * w[c]);
}

// q postprocess: split q (S,3072) into qnope bf16 (S,H*128) and roped pe into
// qf[h][s][512..575]
__global__ void q_post(const float* __restrict__ q, const float* __restrict__ cs,
                       const float* __restrict__ sn, unsigned short* __restrict__ qnope,
                       unsigned short* __restrict__ qf) {
  const int s = blockIdx.x, tid = threadIdx.x;
  const float* qr = q + (long)s * 3072;
  for (int c = tid; c < 3072; c += 256) {
    const int h = c / 192, d = c % 192;
    if (d < 128) {
      qnope[(long)s * 2048 + h * 128 + d] = f2bf(qr[c]);
    } else {
      const int j = d - 128;
      const float x = qr[c];
      const float rot = (j < 32) ? -qr[h * 192 + 128 + j + 32]
                                 :  qr[h * 192 + 128 + j - 32];
      const float v = x * cs[s * 64 + j] + rot * sn[s * 64 + j];
      qf[(long)h * (S_ * 576) + (long)s * 576 + 512 + j] = f2bf(v);
    }
  }
}

// kv postprocess: rmsnorm first 512 -> kf[:, :512] and klat^T; rope last 64.
__global__ void kv_post(const float* __restrict__ kv, const float* __restrict__ w,
                        const float* __restrict__ cs, const float* __restrict__ sn,
                        unsigned short* __restrict__ kf, unsigned short* __restrict__ klt) {
  const int s = blockIdx.x, tid = threadIdx.x;
  const float* kr = kv + (long)s * 576;
  float ss = 0.f;
  for (int c = tid; c < 512; c += 256) { float v = kr[c]; ss += v * v; }
  ss = block_sum256(ss);
  const float rms = rsqrtf(ss / 512.f + 1e-6f);
  for (int c = tid; c < 576; c += 256) {
    if (c < 512) {
      const float v = kr[c] * rms * w[c];
      const unsigned short bv = f2bf(v);
      kf[(long)s * 576 + c] = bv;
      klt[(long)c * S_ + s] = bv;
    } else {
      const int j = c - 512;
      const float x = kr[c];
      const float rot = (j < 32) ? -kr[512 + j + 32] : kr[512 + j - 32];
      kf[(long)s * 576 + c] = f2bf(x * cs[s * 64 + j] + rot * sn[s * 64 + j]);
    }
  }
}

// causal softmax IN-PLACE on bf16 scores. Row r: softmax over c<=r; zeros for
// c in (r, kmax), kmax = 128*ceil((r+1)/128) (cols the causal PV GEMM reads).
__global__ void softmax_causal_ip(unsigned short* __restrict__ sc, long hstride) {
  const int row = blockIdx.x, tid = threadIdx.x;
  unsigned short* sr = sc + (long)blockIdx.z * hstride + (long)row * S_;
  const int n = row + 1;
  const int kmax = ((row >> 7) + 1) << 7;
  float mx = -1e30f;
  for (int c = tid; c < n; c += 256) mx = fmaxf(mx, bf2f(sr[c]));
  mx = block_max256(mx);
  float e[8];
  float sum = 0.f;
  #pragma unroll
  for (int k = 0; k < 8; ++k) {
    const int c = tid + k * 256;
    if (c < n) { e[k] = __expf(bf2f(sr[c]) - mx); sum += e[k]; }
  }
  sum = block_sum256(sum);   // internal syncthreads: all reads of sr done
  const float inv = 1.f / sum;
  #pragma unroll
  for (int k = 0; k < 8; ++k) {
    const int c = tid + k * 256;
    if (c < n) sr[c] = f2bf(e[k] * inv);
    else if (c < kmax) sr[c] = 0;
  }
}

// ---------------------------------------------------------------------------
extern "C" void kernel_launch(void* const* d_in, const int* in_sizes, int n_in,
                              void* d_out, int out_size, void* d_ws, size_t ws_size,
                              hipStream_t stream) {
  const float* hs   = (const float*)d_in[0];
  const float* cs   = (const float*)d_in[1];
  const float* sn   = (const float*)d_in[2];
  const float* ln1  = (const float*)d_in[3];
  const float* qaw  = (const float*)d_in[4];
  const float* qaln = (const float*)d_in[5];
  const float* qbw  = (const float*)d_in[6];
  const float* kvaw = (const float*)d_in[7];
  const float* kvln = (const float*)d_in[8];
  const float* kcw  = (const float*)d_in[9];
  const float* vcw  = (const float*)d_in[10];
  const float* ow   = (const float*)d_in[11];
  const float* ln2  = (const float*)d_in[12];
  const float* guw  = (const float*)d_in[13];
  const float* dww  = (const float*)d_in[14];
  float* out = (float*)d_out;
  char* ws = (char*)d_ws;

  // ---- workspace layout (bytes); high-water 183697408 ----------------------
  // pre-attention (dead before scores are written)
  unsigned short* hbf   = (unsigned short*)(ws + 0);           // S*D bf16 8MB
  float*          qa    = (float*)(ws + 8388608);              // S*QL f32
  unsigned short* qan   = (unsigned short*)(ws + 20971520);    // S*QL bf16
  float*          q     = (float*)(ws + 27262976);             // S*3072 f32
  unsigned short* qnope = (unsigned short*)(ws + 52428800);    // S*2048 bf16 ends 60817408
  // attention
  unsigned short* sc    = (unsigned short*)(ws + 0);           // 8 heads S*S bf16 = 64MB
  unsigned short* qf    = (unsigned short*)(ws + 67108864);    // H*S*576 bf16 ends 104857600
  float*          kv    = (float*)(ws + 104857600);            // S*576 f32
  unsigned short* kf    = (unsigned short*)(ws + 109576192);   // S*576 bf16
  unsigned short* klt   = (unsigned short*)(ws + 111935488);   // 512*S bf16
  unsigned short* wt2   = (unsigned short*)(ws + 114032640);   // vc^T 2MB
  unsigned short* wt    = (unsigned short*)(ws + 116129792);   // weight scratch (<=67MB, ends 183697408)
  unsigned short* olat  = (unsigned short*)(ws + 116129792);   // H*S*512 bf16 (aliases wt; kc^T dead first,
                                                               // wt reused only after olat consumed)
  // post-attention
  unsigned short* obf   = (unsigned short*)(ws + 0);           // S*2048 bf16 8MB
  float*          hidden= (float*)(ws + 8388608);              // S*D f32 ends 25165824
  unsigned short* x2    = (unsigned short*)(ws + 25165824);    // S*D bf16 ends 33554432
  unsigned short* mlp   = (unsigned short*)(ws + 33554432);    // S*I bf16 ends 67108864

  const dim3 B256(256), B512(512);

  // 1. h = rmsnorm(hidden_states, ln1)
  rmsnorm_k<<<S_, B256, 0, stream>>>(hs, ln1, hbf, D_);
  // 2-3. q_a = h @ q_a_w
  transpose64<0><<<dim3(QL_/64, D_/64, 1), B256, 0, stream>>>(qaw, wt, D_, QL_, 0, 0);
  gemm_bt<0,0,0,0><<<dim3(QL_/128, S_/128, 1), B256, 0, stream>>>(
      hbf, wt, qa, nullptr, 1.f, S_, QL_, D_, D_, D_, QL_, 0, 0, 0);
  // 4. q_a_norm
  rmsnorm_k<<<S_, B256, 0, stream>>>(qa, qaln, qan, QL_);
  // 5-6. q = qan @ q_b_w
  transpose64<0><<<dim3(3072/64, QL_/64, 1), B256, 0, stream>>>(qbw, wt, QL_, 3072, 0, 0);
  gemm_bt<0,0,0,0><<<dim3(3072/128, S_/128, 1), B256, 0, stream>>>(
      qan, wt, q, nullptr, 1.f, S_, 3072, QL_, QL_, QL_, 3072, 0, 0, 0);
  // 7. split q -> qnope bf16, rope(q_pe) -> qf[...,512:]
  q_post<<<S_, B256, 0, stream>>>(q, cs, sn, qnope, qf);
  // 8-9. kv = h @ kv_a_w
  transpose64<0><<<dim3(576/64, D_/64, 1), B256, 0, stream>>>(kvaw, wt, D_, 576, 0, 0);
  gemm_bt<0,0,0,0><<<dim3(5, S_/128, 1), B256, 0, stream>>>(
      hbf, wt, kv, nullptr, 1.f, S_, 576, D_, D_, D_, 576, 0, 0, 0);
  // 10. kv_post: k_lat rmsnorm + transpose, k_pe rope
  kv_post<<<S_, B256, 0, stream>>>(kv, kvln, cs, sn, kf, klt);
  // 11-12. transpose kc_w (128x512 -> 512x128 per head) and vc_w (512x128 -> 128x512)
  transpose64<0><<<dim3(512/64, 128/64, H_), B256, 0, stream>>>(kcw, wt, 128, 512, 65536, 65536);
  transpose64<0><<<dim3(128/64, 512/64, H_), B256, 0, stream>>>(vcw, wt2, 512, 128, 65536, 65536);
  // 13. q_lat[h] = qnope[:,h,:] @ kc_w[h] -> qf[h][:, :512]
  gemm_bt<1,0,0,0><<<dim3(4, S_/128, H_), B256, 0, stream>>>(
      qnope, wt, qf, nullptr, 1.f, S_, 512, 128, 2048, 128, 576,
      128, 65536, (long)S_ * 576);
  // 14-19. attention, 2 groups of 8 heads. scores via 256^2 deep-pipe GEMM
  // (lower-triangle of the 8x8 tile grid; cols above the 128-aligned kmax
  // hold garbage that softmax/PV provably never read).
  for (int g = 0; g < 2; ++g) {
    const unsigned short* qfg = qf + (long)g * 8 * S_ * 576;
    gemm256<1,1><<<dim3(36, 1, 8), B512, 0, stream>>>(
        qfg, kf, sc, SCALE_, S_, S_, 576, 576, 576, S_,
        (long)S_ * 576, 0, (long)S_ * S_);
    softmax_causal_ip<<<dim3(S_, 1, 8), B256, 0, stream>>>(sc, (long)S_ * S_);
    gemm_bt<1,0,0,1><<<dim3(4, 16, 8), B256, 0, stream>>>(
        sc, klt, olat + (long)g * 8 * S_ * 512, nullptr, 1.f,
        S_, 512, S_, S_, S_, 512, (long)S_ * S_, 0, (long)S_ * 512);
  }
  // 20. o[:, h*128:...] = o_lat[h] @ vc_w[h]
  gemm_bt<1,0,0,0><<<dim3(1, S_/128, H_), B256, 0, stream>>>(
      olat, wt2, obf, nullptr, 1.f, S_, 128, 512, 512, 512, 2048,
      (long)S_ * 512, 65536, 128);
  // 21-22. hidden = hs + o @ o_w   (residual fused into GEMM epilogue)
  transpose64<0><<<dim3(D_/64, D_/64, 1), B256, 0, stream>>>(ow, wt, D_, D_, 0, 0);
  gemm_bt<0,1,0,0><<<dim3(D_/128, S_/128, 1), B256, 0, stream>>>(
      obf, wt, hidden, hs, 1.f, S_, D_, D_, D_, D_, D_, 0, 0, 0);
  // 23. x2 = rmsnorm(hidden, ln2)
  rmsnorm_k<<<S_, B256, 0, stream>>>(hidden, ln2, x2, D_);
  // 24-25. mlp = silu(x2@gate) * (x2@up) via 256^2 deep-pipe GEMM,
  // silu fused in epilogue, interleaved weight cols, column-major XCD chunks.
  transpose64<1><<<dim3(2 * I_ / 64, D_/64, 1), B256, 0, stream>>>(guw, wt, D_, 2 * I_, 0, 0);
  gemm256<2,0><<<dim3(2 * I_ / 256, S_/256, 1), B512, 0, stream>>>(
      x2, wt, mlp, 1.f, S_, 2 * I_, D_, D_, D_, I_, 0, 0, 0);
  // 26-27. out = hidden + mlp @ down_w
  transpose64<0><<<dim3(D_/64, I_/64, 1), B256, 0, stream>>>(dww, wt, I_, D_, 0, 0);
  gemm_bt<0,1,0,0><<<dim3(D_/128, S_/128, 1), B256, 0, stream>>>(
      mlp, wt, out, hidden, 1.f, S_, D_, I_, I_, I_, D_, 0, 0, 0);
}